// Round 1
// baseline (214.389 us; speedup 1.0000x reference)
//
#include <hip/hip_runtime.h>
#include <math.h>

#define NN 50000
#define NE 800000
#define NR 16
#define NEP_MAX (NE + NR * 16)   // type groups padded to multiples of 16
#define NB 196                   // coarse dst buckets (dst>>8), ceil(50000/256)
#define NBIN 212                 // 196 coarse + 16 type bins
#define ABLK 256                 // blocks in count/scatter passes
#define CHUNK ((NE + ABLK - 1) / ABLK)   // 3125

typedef __attribute__((ext_vector_type(8))) short short8;
typedef __attribute__((ext_vector_type(4))) float floatx4;

__device__ __forceinline__ unsigned short f2bf(float x) {
    unsigned int u = __float_as_uint(x);
    u += 0x7fffu + ((u >> 16) & 1u);
    return (unsigned short)(u >> 16);
}
__device__ __forceinline__ float bf2f(unsigned short s) {
    return __uint_as_float(((unsigned int)s) << 16);
}

// ---------------------------------------------------------------------------
// K1 (fused): blocks [0,64): MFMA-fragment weights (bf16) + attention bias.
//             blocks [64,260): init_fea = concat(feat, embed[idx]) @ T
//             -> out[:,0,:] (fp32) + bf16 copy.
// ---------------------------------------------------------------------------
__global__ void k_pre(const float* __restrict__ feat, const float* __restrict__ emb,
                      const float* __restrict__ T, const int* __restrict__ idx,
                      const float* __restrict__ weight, const float* __restrict__ w_comp,
                      const float* __restrict__ A_w, const float* __restrict__ A_b,
                      const float* __restrict__ attn_emb,
                      float* __restrict__ out, unsigned short* __restrict__ init_bf,
                      unsigned short* __restrict__ wfrag, unsigned short* __restrict__ afrag,
                      float* __restrict__ aproj) {
    if (blockIdx.x < 64) {
        int g = blockIdx.x * 256 + threadIdx.x;          // g < 16384 always
        {                                                // wfrag: 16384 (1024 per type)
            int t = g >> 10, rest = g & 1023;
            int nt = rest >> 9, l = (rest >> 3) & 63, j = rest & 7;
            int k = (l >> 4) * 8 + j, n = (l & 15) + 16 * nt;
            float acc = 0.f;
#pragma unroll
            for (int b = 0; b < 4; b++) acc += w_comp[t * 4 + b] * weight[b * 1024 + k * 32 + n];
            wfrag[g] = f2bf(acc);
        }
        if (g < 2 * 2 * 64 * 8) {                        // afrag: 2048 (1024 per ks)
            int ks = g >> 10, rest = g & 1023;
            int nt = rest >> 9, l = (rest >> 3) & 63, j = rest & 7;
            int k = ks * 32 + (l >> 4) * 8 + j, n = (l & 15) + 16 * nt;
            afrag[g] = f2bf(A_w[k * 32 + n]);
        }
        if (g < 16 * 32) {                               // aproj: 512
            int t = g >> 5, j = g & 31;
            float acc = A_b[j];
#pragma unroll
            for (int k = 0; k < 32; k++) acc += attn_emb[t * 32 + k] * A_w[(64 + k) * 32 + j];
            aproj[g] = acc;
        }
        return;
    }
    int i = (blockIdx.x - 64) * 256 + threadIdx.x;
    if (i >= NN) return;
    float v[32], acc[32];
#pragma unroll
    for (int o = 0; o < 32; o++) acc[o] = 0.f;
    const float4* fp = (const float4*)(feat + (size_t)i * 32);
#pragma unroll
    for (int q = 0; q < 8; q++) {
        float4 f = fp[q];
        v[4 * q] = f.x; v[4 * q + 1] = f.y; v[4 * q + 2] = f.z; v[4 * q + 3] = f.w;
    }
#pragma unroll
    for (int d = 0; d < 32; d++) {
        float xd = v[d];
#pragma unroll
        for (int o = 0; o < 32; o++) acc[o] += xd * T[d * 32 + o];
    }
    int row = idx[i];
    const float4* ep = (const float4*)(emb + (size_t)row * 32);
#pragma unroll
    for (int q = 0; q < 8; q++) {
        float4 f = ep[q];
        v[4 * q] = f.x; v[4 * q + 1] = f.y; v[4 * q + 2] = f.z; v[4 * q + 3] = f.w;
    }
#pragma unroll
    for (int d = 0; d < 32; d++) {
        float xd = v[d];
#pragma unroll
        for (int o = 0; o < 32; o++) acc[o] += xd * T[(32 + d) * 32 + o];
    }
    float4* op = (float4*)(out + (size_t)i * 64);
#pragma unroll
    for (int q = 0; q < 8; q++) {
        float4 f;
        f.x = acc[4 * q]; f.y = acc[4 * q + 1]; f.z = acc[4 * q + 2]; f.w = acc[4 * q + 3];
        op[q] = f;
    }
    unsigned int w[16];
#pragma unroll
    for (int q = 0; q < 16; q++)
        w[q] = (unsigned int)f2bf(acc[2 * q]) | ((unsigned int)f2bf(acc[2 * q + 1]) << 16);
    uint4* bp = (uint4*)(init_bf + (size_t)i * 32);
#pragma unroll
    for (int q = 0; q < 4; q++) {
        uint4 u; u.x = w[4 * q]; u.y = w[4 * q + 1]; u.z = w[4 * q + 2]; u.w = w[4 * q + 3];
        bp[q] = u;
    }
}

// ---------------------------------------------------------------------------
// K3: per-block LDS histogram of coarse dst bucket (dst>>8) + type bins.
// 1024 threads/block (4 waves/SIMD) so global-load latency is hidden —
// at 256 threads these blocks ran at 1 wave/SIMD, pure latency-bound.
// ---------------------------------------------------------------------------
__global__ void __launch_bounds__(1024) k_count(const int* __restrict__ ed,
                                                const int* __restrict__ et,
                                                int* __restrict__ cpb) {
    __shared__ int lc[NBIN];
    for (int i = threadIdx.x; i < NBIN; i += 1024) lc[i] = 0;
    __syncthreads();
    const int start = blockIdx.x * CHUNK, end = min(start + CHUNK, NE);
    for (int e = start + threadIdx.x; e < end; e += 1024) {
        atomicAdd(&lc[ed[e] >> 8], 1);
        atomicAdd(&lc[NB + et[e]], 1);
    }
    __syncthreads();
    for (int i = threadIdx.x; i < NBIN; i += 1024) cpb[blockIdx.x * NBIN + i] = lc[i];
}

// ---------------------------------------------------------------------------
// K4: single-block scan. Writes per-block exclusive cursors to a SEPARATE
// array cpbx (the in-place version load/store-aliased on cpb and serialized
// into 256 L2 round-trips). Totals -> boff (coarse) and toff/tend (types).
// ---------------------------------------------------------------------------
__global__ void __launch_bounds__(256) k_scanB(const int* __restrict__ cpb,
                                               int* __restrict__ cpbx,
                                               int* __restrict__ boff,
                                               int* __restrict__ toff,
                                               int* __restrict__ tend) {
    __shared__ int tot[NBIN];
    int bin = threadIdx.x;
    if (bin < NBIN) {
        int run = 0;
#pragma unroll 8
        for (int c = 0; c < ABLK; c++) {
            int v = cpb[c * NBIN + bin];
            cpbx[c * NBIN + bin] = run;
            run += v;
        }
        tot[bin] = run;
    }
    __syncthreads();
    if (threadIdx.x == 0) {
        int acc = 0;
        for (int b = 0; b < NB; b++) { boff[b] = acc; acc += tot[b]; }
        boff[NB] = acc;                          // == NE
        int t0 = 0;
        for (int t = 0; t < NR; t++) {
            toff[t] = t0;
            tend[t] = t0 + tot[NB + t];
            t0 += ((tot[NB + t] + 15) >> 4) << 4;
        }
        toff[NR] = t0;
    }
}

// ---------------------------------------------------------------------------
// K5: scatter with precomputed cursors (LDS atomics only). 1024 threads/block
// for latency hiding. Assigns both the type-sorted slot q (-> tsrc/tdst) and
// the coarse-bucket slot (-> bpack = (q<<8)|(dst&255)).
// ---------------------------------------------------------------------------
__global__ void __launch_bounds__(1024) k_scatA(const int* __restrict__ es,
                                                const int* __restrict__ ed,
                                                const int* __restrict__ et,
                                                const int* __restrict__ cpbx,
                                                const int* __restrict__ boff,
                                                const int* __restrict__ toff,
                                                int* __restrict__ tsrc,
                                                int* __restrict__ tdst,
                                                int* __restrict__ bpack) {
    __shared__ int cur[NBIN];
    const int start = blockIdx.x * CHUNK, end = min(start + CHUNK, NE);
    for (int i = threadIdx.x; i < NBIN; i += 1024) {
        int base = (i < NB) ? boff[i] : toff[i - NB];
        cur[i] = base + cpbx[blockIdx.x * NBIN + i];
    }
    __syncthreads();
    for (int e = start + threadIdx.x; e < end; e += 1024) {
        int s = es[e], d = ed[e], t = et[e];
        int q = atomicAdd(&cur[NB + t], 1);
        int slot = atomicAdd(&cur[d >> 8], 1);
        tsrc[q] = s;
        tdst[q] = d;
        bpack[slot] = (q << 8) | (d & 255);
    }
}

// ---------------------------------------------------------------------------
// K6: fine counting sort within each 256-node bucket (one block per bucket).
// Produces row_off (CSR by dst) and the permutation p_of_q so k_msg can
// write amsg directly in dst-sorted order. LDS atomics only.
// ---------------------------------------------------------------------------
__global__ void __launch_bounds__(256) k_fine(const int* __restrict__ boff,
                                              const int* __restrict__ bpack,
                                              int* __restrict__ row_off,
                                              int* __restrict__ p_of_q) {
    __shared__ int h[256], ls[256];
    const int b = blockIdx.x;
    const int s0 = boff[b], s1 = boff[b + 1];
    const int tid = threadIdx.x;
    h[tid] = 0;
    __syncthreads();
    for (int s = s0 + tid; s < s1; s += 256)
        atomicAdd(&h[bpack[s] & 255], 1);
    __syncthreads();
    int v = h[tid];
    ls[tid] = v;
    __syncthreads();
    for (int off = 1; off < 256; off <<= 1) {
        int t = (tid >= off) ? ls[tid - off] : 0;
        __syncthreads();
        ls[tid] += t;
        __syncthreads();
    }
    int excl = ls[tid] - v;                  // exclusive prefix of fine bins
    int node = b * 256 + tid;
    if (node <= NN) row_off[node] = s0 + excl;  // covers row_off[NN]=NE too
    h[tid] = s0 + excl;                      // reuse h as global-position cursor
    __syncthreads();
    for (int s = s0 + tid; s < s1; s += 256) {
        int pk = bpack[s];
        int p = atomicAdd(&h[pk & 255], 1);
        p_of_q[pk >> 8] = p;
    }
}

// ---------------------------------------------------------------------------
// K7: type-major MFMA kernel. One 16-edge type-pure tile per wave, no LDS.
//   msg = x @ W_t; hid = x @ A_w0 + y @ A_w1 + aproj[t]
//   a = sigmoid(relu(hid) . B_w + B_b); amsg[p_of_q[q]] = bf16(a * msg)
// ---------------------------------------------------------------------------
__global__ void __launch_bounds__(256) k_msg(
    const unsigned short* __restrict__ wfrag, const unsigned short* __restrict__ afrag,
    const float* __restrict__ aproj, const float* __restrict__ B_w,
    const float* __restrict__ B_b, const int* __restrict__ toff,
    const int* __restrict__ tend, const int* __restrict__ tsrc,
    const int* __restrict__ tdst, const int* __restrict__ p_of_q,
    const unsigned short* __restrict__ init_bf, unsigned short* __restrict__ amsg) {
    const int wave = threadIdx.x >> 6;
    const int lane = threadIdx.x & 63;
    const int q0 = (blockIdx.x * 4 + wave) * 16;
    if (q0 >= toff[NR]) return;
    int t = 0;
#pragma unroll
    for (int i = 1; i < NR; i++) t += (q0 >= toff[i]) ? 1 : 0;
    t = __builtin_amdgcn_readfirstlane(t);
    const int te = tend[t];
    const int m = lane & 15, quad = lane >> 4;
    const int qa = q0 + m;
    const bool va = qa < te;
    int src = va ? tsrc[qa] : 0;
    int dst = va ? tdst[qa] : 0;
    short8 xa = *(const short8*)(init_bf + (size_t)src * 32 + quad * 8);
    short8 ya = *(const short8*)(init_bf + (size_t)dst * 32 + quad * 8);
    short8 wb0 = *(const short8*)(wfrag + (size_t)((t * 2 + 0) * 64 + lane) * 8);
    short8 wb1 = *(const short8*)(wfrag + (size_t)((t * 2 + 1) * 64 + lane) * 8);
    short8 a00 = *(const short8*)(afrag + (size_t)((0 * 2 + 0) * 64 + lane) * 8);
    short8 a01 = *(const short8*)(afrag + (size_t)((0 * 2 + 1) * 64 + lane) * 8);
    short8 a10 = *(const short8*)(afrag + (size_t)((1 * 2 + 0) * 64 + lane) * 8);
    short8 a11 = *(const short8*)(afrag + (size_t)((1 * 2 + 1) * 64 + lane) * 8);
    floatx4 z4 = {0.f, 0.f, 0.f, 0.f};
    floatx4 mc0 = __builtin_amdgcn_mfma_f32_16x16x32_bf16(xa, wb0, z4, 0, 0, 0);
    floatx4 mc1 = __builtin_amdgcn_mfma_f32_16x16x32_bf16(xa, wb1, z4, 0, 0, 0);
    floatx4 hc0 = __builtin_amdgcn_mfma_f32_16x16x32_bf16(xa, a00, z4, 0, 0, 0);
    hc0 = __builtin_amdgcn_mfma_f32_16x16x32_bf16(ya, a10, hc0, 0, 0, 0);
    floatx4 hc1 = __builtin_amdgcn_mfma_f32_16x16x32_bf16(xa, a01, z4, 0, 0, 0);
    hc1 = __builtin_amdgcn_mfma_f32_16x16x32_bf16(ya, a11, hc1, 0, 0, 0);
    const int col = m;
    float ap0 = aproj[t * 32 + col], ap1 = aproj[t * 32 + 16 + col];
    float bw0 = B_w[col], bw1 = B_w[col + 16];
    float bb = B_b[0];
    float part[4];
#pragma unroll
    for (int r = 0; r < 4; r++)
        part[r] = fmaxf(hc0[r] + ap0, 0.f) * bw0 + fmaxf(hc1[r] + ap1, 0.f) * bw1;
#pragma unroll
    for (int s = 1; s < 16; s <<= 1) {
#pragma unroll
        for (int r = 0; r < 4; r++) part[r] += __shfl_xor(part[r], s, 64);
    }
#pragma unroll
    for (int r = 0; r < 4; r++) {
        int qe = q0 + quad * 4 + r;
        if (qe < te) {
            int pe = p_of_q[qe];
            float a = 1.f / (1.f + __expf(-(part[r] + bb)));
            amsg[(size_t)pe * 32 + col] = f2bf(a * mc0[r]);
            amsg[(size_t)pe * 32 + col + 16] = f2bf(a * mc1[r]);
        }
    }
}

// ---------------------------------------------------------------------------
// K8: dst-major aggregation + fused self-loop GEMM + ReLU (streaming amsg).
// ---------------------------------------------------------------------------
__global__ void __launch_bounds__(256) k_agg(
    const int* __restrict__ row_off, const unsigned short* __restrict__ amsg,
    const float* __restrict__ S, float* __restrict__ out) {
    int tid = threadIdx.x;
    int v = blockIdx.x * 64 + (tid >> 2);
    if (v >= NN) return;
    int c0 = (tid & 3) * 8;
    float acc[8];
#pragma unroll
    for (int j = 0; j < 8; j++) acc[j] = 0.f;
    int p0 = row_off[v], p1 = row_off[v + 1];
    for (int p = p0; p < p1; p++) {
        short8 mv = *(const short8*)(amsg + (size_t)p * 32 + c0);
#pragma unroll
        for (int j = 0; j < 8; j++) acc[j] += bf2f((unsigned short)mv[j]);
    }
    float x[32];
    const float4* xp = (const float4*)(out + (size_t)v * 64);
#pragma unroll
    for (int q = 0; q < 8; q++) {
        float4 f = xp[q];
        x[4 * q] = f.x; x[4 * q + 1] = f.y; x[4 * q + 2] = f.z; x[4 * q + 3] = f.w;
    }
#pragma unroll
    for (int d = 0; d < 32; d++) {
        float xd = x[d];
#pragma unroll
        for (int j = 0; j < 8; j++) acc[j] += xd * S[d * 32 + c0 + j];
    }
    float4* op = (float4*)(out + (size_t)v * 64 + 32 + c0);
#pragma unroll
    for (int q = 0; q < 2; q++) {
        float4 f;
        f.x = fmaxf(acc[4 * q], 0.f);
        f.y = fmaxf(acc[4 * q + 1], 0.f);
        f.z = fmaxf(acc[4 * q + 2], 0.f);
        f.w = fmaxf(acc[4 * q + 3], 0.f);
        op[q] = f;
    }
}

extern "C" void kernel_launch(void* const* d_in, const int* in_sizes, int n_in,
                              void* d_out, int out_size, void* d_ws, size_t ws_size,
                              hipStream_t stream) {
    const float* feat      = (const float*)d_in[0];
    const float* embed     = (const float*)d_in[1];
    const float* transform = (const float*)d_in[2];
    const float* weight    = (const float*)d_in[3];
    const float* w_comp    = (const float*)d_in[4];
    const float* self_w    = (const float*)d_in[5];
    const float* A_w       = (const float*)d_in[6];
    const float* A_b       = (const float*)d_in[7];
    const float* B_w       = (const float*)d_in[8];
    const float* B_b       = (const float*)d_in[9];
    const float* attn_emb  = (const float*)d_in[10];
    const int*   idx       = (const int*)d_in[11];
    const int*   edge_src  = (const int*)d_in[12];
    const int*   edge_dst  = (const int*)d_in[13];
    const int*   edge_type = (const int*)d_in[14];
    float* out = (float*)d_out;

    // -------- workspace layout --------
    char* ws = (char*)d_ws;
    unsigned short* amsg    = (unsigned short*)ws;                 // NEP_MAX*64 B = 51,216,384
    int*            bpack   = (int*)ws;      // aliases amsg[0 .. NE*4B): consumed by k_fine
                                             // BEFORE k_msg overwrites the region.
    unsigned short* init_bf = (unsigned short*)(ws + (size_t)NEP_MAX * 64);          // 3,200,000 B
    unsigned short* wfrag   = (unsigned short*)((char*)init_bf + 3200000);           // 32,768 B
    unsigned short* afrag   = (unsigned short*)((char*)wfrag + 32768);               // 4,096 B
    float*          aproj   = (float*)((char*)afrag + 4096);                         // 2,048 B
    int* ip       = (int*)((char*)aproj + 2048);
    int* toff     = ip;              ip += 32;          // 17 used
    int* tend     = ip;              ip += 16;
    int* boff     = ip;              ip += 200;         // 197 used
    int* cpb      = ip;              ip += ABLK * NBIN; // 54,272
    int* cpbx     = ip;              ip += ABLK * NBIN; // 54,272 (separate scan output)
    int* row_off  = ip;              ip += NN + 1;
    int* tsrc     = ip;              ip += NEP_MAX;
    int* tdst     = ip;              ip += NEP_MAX;
    int* p_of_q   = ip;              ip += NEP_MAX;     // total ~64.7 MB

    k_pre<<<260, 256, 0, stream>>>(feat, embed, transform, idx, weight, w_comp,
                                   A_w, A_b, attn_emb, out, init_bf, wfrag, afrag, aproj);
    k_count<<<ABLK, 1024, 0, stream>>>(edge_dst, edge_type, cpb);
    k_scanB<<<1, 256, 0, stream>>>(cpb, cpbx, boff, toff, tend);
    k_scatA<<<ABLK, 1024, 0, stream>>>(edge_src, edge_dst, edge_type, cpbx, boff, toff,
                                       tsrc, tdst, bpack);
    k_fine<<<NB, 256, 0, stream>>>(boff, bpack, row_off, p_of_q);
    const int tiles = NEP_MAX / 16;                    // 50016
    k_msg<<<(tiles + 3) / 4, 256, 0, stream>>>(wfrag, afrag, aproj, B_w, B_b,
                                               toff, tend, tsrc, tdst, p_of_q,
                                               init_bf, amsg);
    k_agg<<<(NN + 63) / 64, 256, 0, stream>>>(row_off, amsg, self_w, out);
}